// Round 1
// baseline (3456.420 us; speedup 1.0000x reference)
//
#include <hip/hip_runtime.h>
#include <math.h>

// Problem constants (from reference)
#define BB   4
#define NN   65536
#define KK   9
#define CIN  64
#define COUT 64

__device__ __forceinline__ float elu_f(float v) {
    // jax.nn.elu with alpha=1: x>0 ? x : expm1(x)
    return v > 0.0f ? v : (__expf(v) - 1.0f);
}

// One wave (64 lanes) per point (b,n); lane == channel index.
// Stage 1: y[t][f] = sum_k x_nb[k][f] * A[n][k][t]   (lane = f)
// Stage 2: z[t][o] = bias[o] + sum_f W[o][f]*elu(y[t][f])  (lane = o)
// out[b][n][o] = max_t elu(z[t][o]);   row n = N-1 zeroed.
__global__ __launch_bounds__(256, 4) void paiconv_kernel(
    const float* __restrict__ x,        // (B, N, CIN)
    const int*   __restrict__ nbr,      // (B, N, KK) int32
    const float* __restrict__ conv_w,   // (COUT, CIN)
    const float* __restrict__ conv_b,   // (COUT,)
    const float* __restrict__ adjw,     // (N, KK, KK)
    float*       __restrict__ out)      // (B, N, COUT)
{
    __shared__ float ey_lds[4][KK * CIN];   // per-wave slices, 9216 B total

    const int lane = threadIdx.x & 63;
    const int wid  = threadIdx.x >> 6;
    const int wave_global = blockIdx.x * 4 + wid;
    const int nwaves      = gridDim.x * 4;

    // Pin this lane's W row (row o = lane) in registers: 16 x float4 = 64 VGPRs
    float4 w4[16];
    const float4* wrow = (const float4*)(conv_w + (size_t)lane * CIN);
    #pragma unroll
    for (int j = 0; j < 16; ++j) w4[j] = wrow[j];
    const float bias = conv_b[lane];

    float* eyw = ey_lds[wid];

    for (int p = wave_global; p < BB * NN; p += nwaves) {
        const int b = p >> 16;        // p / NN
        const int n = p & (NN - 1);   // p % NN

        // Gather the 9 neighbor rows; lane f reads element f of each row
        // (64 consecutive floats per row -> one coalesced 256B request).
        const int* nb = nbr + ((size_t)b * NN + n) * KK;
        float xnb[KK];
        #pragma unroll
        for (int k = 0; k < KK; ++k) {
            const int idx = nb[k];    // wave-uniform broadcast load
            xnb[k] = x[((size_t)b * NN + idx) * CIN + lane];
        }

        // Stage 1 + elu -> per-wave LDS slice (write: 2 lanes/bank = free)
        const float* An = adjw + (size_t)n * (KK * KK);
        #pragma unroll
        for (int t = 0; t < KK; ++t) {
            float y = 0.0f;
            #pragma unroll
            for (int k = 0; k < KK; ++k)
                y += xnb[k] * An[k * KK + t];   // A load is wave-uniform
            eyw[t * CIN + lane] = elu_f(y);
        }
        // Intra-wave LDS RAW: compiler inserts s_waitcnt lgkmcnt; no barrier
        // needed (each wave owns its slice).

        // Stage 2: lane o dot-products its W row with ey[t][*] (LDS reads are
        // same-address broadcasts across the wave -> conflict-free).
        float m = -INFINITY;
        #pragma unroll
        for (int t = 0; t < KK; ++t) {
            float z = bias;
            const float4* e4 = (const float4*)(eyw + t * CIN);
            #pragma unroll
            for (int j = 0; j < 16; ++j) {
                const float4 e = e4[j];
                z = fmaf(w4[j].x, e.x, z);
                z = fmaf(w4[j].y, e.y, z);
                z = fmaf(w4[j].z, e.z, z);
                z = fmaf(w4[j].w, e.w, z);
            }
            m = fmaxf(m, elu_f(z));
        }

        if (n == NN - 1) m = 0.0f;   // zero_pad: row N-1 zeroed for all b
        out[((size_t)b * NN + n) * COUT + lane] = m;
    }
}

extern "C" void kernel_launch(void* const* d_in, const int* in_sizes, int n_in,
                              void* d_out, int out_size, void* d_ws, size_t ws_size,
                              hipStream_t stream) {
    const float* x      = (const float*)d_in[0];
    // d_in[1] = t_vertex: unused by the reference
    const int*   nbr    = (const int*)d_in[2];
    const float* conv_w = (const float*)d_in[3];
    const float* conv_b = (const float*)d_in[4];
    const float* adjw   = (const float*)d_in[5];
    float*       out    = (float*)d_out;

    dim3 grid(2048), block(256);   // 8192 waves, 32 points/wave grid-stride
    hipLaunchKernelGGL(paiconv_kernel, grid, block, 0, stream,
                       x, nbr, conv_w, conv_b, adjw, out);
}

// Round 2
// 1205.465 us; speedup vs baseline: 2.8673x; 2.8673x over previous
//
#include <hip/hip_runtime.h>
#include <math.h>

// Problem constants (from reference)
#define BB   4
#define NN   65536
#define KK   9
#define CIN  64
#define COUT 64

__device__ __forceinline__ float elu_f(float v) {
    return v > 0.0f ? v : (__expf(v) - 1.0f);
}

// One wave (64 lanes) per point (b,n); lane == channel index.
// Stage 1: y[t][f] = sum_k x_nb[k][f] * A[n][k][t]   (lane = f)
// Stage 2: z[t][o] = bias[o] + sum_f W[o][f]*elu(y[t][f])  (lane = o)
// out[b][n][o] = max_t elu(z[t][o]);   row n = N-1 zeroed.
//
// R2: __launch_bounds__(256,2) — R1's (256,4) forced VGPR_Count=64 and
// spilled the 64-reg W array to scratch (FETCH 11.9 GB vs 0.7 GB logical).
__global__ __launch_bounds__(256, 2) void paiconv_kernel(
    const float* __restrict__ x,        // (B, N, CIN)
    const int*   __restrict__ nbr,      // (B, N, KK) int32
    const float* __restrict__ conv_w,   // (COUT, CIN)
    const float* __restrict__ conv_b,   // (COUT,)
    const float* __restrict__ adjw,     // (N, KK, KK)
    float*       __restrict__ out)      // (B, N, COUT)
{
    __shared__ float ey_lds[4][KK * CIN];   // per-wave slices, 9216 B total

    const int lane = threadIdx.x & 63;
    const int wid  = threadIdx.x >> 6;
    const int wave_global = blockIdx.x * 4 + wid;
    const int nwaves      = gridDim.x * 4;

    // Pin this lane's W row (row o = lane): 16 x float4 = 64 VGPRs.
    float4 w4[16];
    const float4* wrow = (const float4*)(conv_w + (size_t)lane * CIN);
    #pragma unroll
    for (int j = 0; j < 16; ++j) w4[j] = wrow[j];
    const float bias = conv_b[lane];

    float* eyw = ey_lds[wid];

    for (int p = wave_global; p < BB * NN; p += nwaves) {
        const int b = p >> 16;        // p / NN
        const int n = p & (NN - 1);   // p % NN

        // Gather 9 neighbor rows; lane f reads element f of each row
        // (64 consecutive floats per row -> one coalesced 256B request).
        const int* nb = nbr + ((size_t)b * NN + n) * KK;
        float xnb[KK];
        #pragma unroll
        for (int k = 0; k < KK; ++k) {
            const int idx = nb[k];    // wave-uniform
            xnb[k] = x[((size_t)b * NN + idx) * CIN + lane];
        }

        // Stage 1 + elu -> per-wave LDS slice (2 lanes/bank write = free).
        const float* An = adjw + (size_t)n * (KK * KK);
        #pragma unroll
        for (int t = 0; t < KK; ++t) {
            float y = 0.0f;
            #pragma unroll
            for (int k = 0; k < KK; ++k)
                y += xnb[k] * An[k * KK + t];
            eyw[t * CIN + lane] = elu_f(y);
        }
        // Intra-wave LDS RAW only — no __syncthreads needed.

        // Stage 2: lane o dot-products its W row with ey[t][*]
        // (LDS reads are same-address broadcasts -> conflict-free).
        float m = -INFINITY;
        #pragma unroll
        for (int t = 0; t < KK; ++t) {
            float z = bias;
            const float4* e4 = (const float4*)(eyw + t * CIN);
            #pragma unroll
            for (int j = 0; j < 16; ++j) {
                const float4 e = e4[j];
                z = fmaf(w4[j].x, e.x, z);
                z = fmaf(w4[j].y, e.y, z);
                z = fmaf(w4[j].z, e.z, z);
                z = fmaf(w4[j].w, e.w, z);
            }
            m = fmaxf(m, elu_f(z));
        }

        if (n == NN - 1) m = 0.0f;   // zero_pad row N-1, all b
        out[((size_t)b * NN + n) * COUT + lane] = m;
    }
}

extern "C" void kernel_launch(void* const* d_in, const int* in_sizes, int n_in,
                              void* d_out, int out_size, void* d_ws, size_t ws_size,
                              hipStream_t stream) {
    const float* x      = (const float*)d_in[0];
    // d_in[1] = t_vertex: unused by the reference
    const int*   nbr    = (const int*)d_in[2];
    const float* conv_w = (const float*)d_in[3];
    const float* conv_b = (const float*)d_in[4];
    const float* adjw   = (const float*)d_in[5];
    float*       out    = (float*)d_out;

    dim3 grid(2048), block(256);   // 8192 waves, 32 points/wave grid-stride
    hipLaunchKernelGGL(paiconv_kernel, grid, block, 0, stream,
                       x, nbr, conv_w, conv_b, adjw, out);
}

// Round 3
// 303.181 us; speedup vs baseline: 11.4005x; 3.9761x over previous
//
#include <hip/hip_runtime.h>
#include <math.h>

// Problem constants
#define BB   4
#define NN   65536
#define KK   9
#define CC   64          // in = out channels
#define ROWS 16          // t padded 9 -> 16 (one MFMA M-tile per point)
#define LDST 72          // LDS row stride in f16 elems (144 B: 16B-aligned, 2-way banks)

typedef _Float16 half8 __attribute__((ext_vector_type(8)));
typedef float   floatx4 __attribute__((ext_vector_type(4)));

__device__ __forceinline__ float elu_f(float v) {
    return v > 0.0f ? v : (__expf(v) - 1.0f);
}

// One wave per point (b,n).
//  stage-1 (VALU): y[t][f] = sum_k x_nb[k][f]*A[n][k][t], lane=f; elu -> f16 -> LDS
//  stage-2 (MFMA): z[t][o] = ey(16x64) . W^T(64x64) via 4 n-tiles x 2 k-steps
//  epilogue: elu(z+bias), masked max over t<9, cross-quad shfl max, store.
// All LDS dependencies are intra-wave: no __syncthreads anywhere.
__global__ __launch_bounds__(256) void paiconv_mfma(
    const float* __restrict__ x,        // (B,N,64)
    const int*   __restrict__ nbr,      // (B,N,9)
    const float* __restrict__ conv_w,   // (64,64)
    const float* __restrict__ conv_b,   // (64,)
    const float* __restrict__ adjw,     // (N,9,9)
    float*       __restrict__ out)      // (B,N,64)
{
    __shared__ __align__(16) _Float16 ey_lds[4][ROWS * LDST];  // 4x2304 B

    const int lane = threadIdx.x & 63;
    const int wid  = threadIdx.x >> 6;
    const int quad = lane >> 4;
    const int c    = lane & 15;

    // B-fragments (held whole kernel): bfrag[s][nt][j] = W[nt*16+c][s*32+quad*8+j]
    // B-layout for 16x16x32: lane holds B[k=quad*8+j][n=lane&15]; here B=W^T.
    half8 bfrag[2][4];
    #pragma unroll
    for (int s = 0; s < 2; ++s)
        #pragma unroll
        for (int nt = 0; nt < 4; ++nt) {
            const float* wp = conv_w + (nt * 16 + c) * CC + s * 32 + quad * 8;
            half8 f;
            #pragma unroll
            for (int j = 0; j < 8; ++j) f[j] = (_Float16)wp[j];
            bfrag[s][nt] = f;
        }
    float biasv[4];
    #pragma unroll
    for (int nt = 0; nt < 4; ++nt) biasv[nt] = conv_b[nt * 16 + c];

    _Float16* eyw = &ey_lds[wid][0];
    const int wave_global = blockIdx.x * 4 + wid;
    const int nwaves      = gridDim.x * 4;

    for (int p = wave_global; p < BB * NN; p += nwaves) {
        // Force wave-uniform scalars so nbr/adjw loads become s_load.
        const int pu = __builtin_amdgcn_readfirstlane(p);
        const int b  = pu >> 16;
        const int n  = pu & (NN - 1);

        // Gather 9 neighbor rows (lane = f): coalesced 256B requests.
        const int* nb = nbr + ((size_t)pu) * KK;
        float xnb[KK];
        #pragma unroll
        for (int k = 0; k < KK; ++k) {
            const int idx = nb[k];                      // s_load (uniform)
            xnb[k] = x[(((size_t)b << 16) + idx) * CC + lane];
        }

        // Stage-1: 81 FMA (adjw operands in SGPRs), elu, f16, LDS write.
        const float* An = adjw + (size_t)n * (KK * KK);
        #pragma unroll
        for (int t = 0; t < KK; ++t) {
            float y = 0.0f;
            #pragma unroll
            for (int k = 0; k < KK; ++k) y = fmaf(xnb[k], An[k * KK + t], y);
            eyw[t * LDST + lane] = (_Float16)elu_f(y);  // 2 lanes/bank: free
        }
        // (rows 9..15 left stale: their MFMA output rows are masked below)

        // A-frags: lane holds A[m=lane&15][k=quad*8+j]; both 16B-aligned.
        const _Float16* ap = eyw + c * LDST + quad * 8;
        const half8 a0 = *(const half8*)(ap);        // f = quad*8 + j
        const half8 a1 = *(const half8*)(ap + 32);   // f = 32 + quad*8 + j

        floatx4 acc[4];
        #pragma unroll
        for (int nt = 0; nt < 4; ++nt) {
            acc[nt] = (floatx4){0.f, 0.f, 0.f, 0.f};
            acc[nt] = __builtin_amdgcn_mfma_f32_16x16x32_f16(a0, bfrag[0][nt], acc[nt], 0, 0, 0);
            acc[nt] = __builtin_amdgcn_mfma_f32_16x16x32_f16(a1, bfrag[1][nt], acc[nt], 0, 0, 0);
        }

        // Epilogue: D[row=quad*4+r][o=nt*16+c]; elu(z+bias); max over rows<9.
        float vmax[4];
        #pragma unroll
        for (int nt = 0; nt < 4; ++nt) {
            float m = -INFINITY;
            #pragma unroll
            for (int r = 0; r < 4; ++r) {
                const float h = elu_f(acc[nt][r] + biasv[nt]);
                if (quad * 4 + r < KK) m = fmaxf(m, h);   // mask pad rows
            }
            vmax[nt] = m;
        }
        // Cross-quad max (lanes c, c+16, c+32, c+48 hold rows of same o).
        #pragma unroll
        for (int nt = 0; nt < 4; ++nt) {
            vmax[nt] = fmaxf(vmax[nt], __shfl_xor(vmax[nt], 16, 64));
            vmax[nt] = fmaxf(vmax[nt], __shfl_xor(vmax[nt], 32, 64));
        }
        // Lane (quad q, c) emits o = q*16 + c == lane: coalesced 256B store.
        float res = (quad == 0) ? vmax[0] : (quad == 1) ? vmax[1]
                  : (quad == 2) ? vmax[2] : vmax[3];
        if (n == NN - 1) res = 0.0f;                  // zero_pad row, all b
        out[((size_t)pu) * CC + lane] = res;
    }
}

extern "C" void kernel_launch(void* const* d_in, const int* in_sizes, int n_in,
                              void* d_out, int out_size, void* d_ws, size_t ws_size,
                              hipStream_t stream) {
    const float* x      = (const float*)d_in[0];
    // d_in[1] = t_vertex: unused by the reference
    const int*   nbr    = (const int*)d_in[2];
    const float* conv_w = (const float*)d_in[3];
    const float* conv_b = (const float*)d_in[4];
    const float* adjw   = (const float*)d_in[5];
    float*       out    = (float*)d_out;

    dim3 grid(2048), block(256);   // 8192 waves, 32 points/wave
    hipLaunchKernelGGL(paiconv_mfma, grid, block, 0, stream,
                       x, nbr, conv_w, conv_b, adjw, out);
}

// Round 4
// 266.056 us; speedup vs baseline: 12.9913x; 1.1395x over previous
//
#include <hip/hip_runtime.h>
#include <math.h>

// Problem constants
#define BB   4
#define NN   65536
#define KK   9
#define CC   64          // in = out channels
#define ROWS 16          // t padded 9 -> 16 (one MFMA M-tile per point)
#define LDST 72          // LDS row stride in f16 elems (144 B: 16B-aligned, 2-way banks)

typedef _Float16 half8 __attribute__((ext_vector_type(8)));
typedef float   floatx4 __attribute__((ext_vector_type(4)));

__device__ __forceinline__ float elu_f(float v) {
    return v > 0.0f ? v : (__expf(v) - 1.0f);
}

// One wave per point (b,n).
//  stage-1 (VALU): y[t][f] = sum_k x_nb[k][f]*A[n][k][t], lane=f; elu -> f16 -> LDS
//  stage-2 (MFMA): z[t][o] = ey(16x64) . W^T(64x64) via 4 n-tiles x 2 k-steps
//  epilogue (R4): ELU is monotone increasing, so max_t elu(z+b) = elu(max_t z + b).
//    Max raw accumulators (masked t<9), 3-shuffle cross-quad reduce, ONE bias+elu.
// All LDS dependencies are intra-wave: no __syncthreads anywhere.
__global__ __launch_bounds__(256) void paiconv_mfma(
    const float* __restrict__ x,        // (B,N,64)
    const int*   __restrict__ nbr,      // (B,N,9)
    const float* __restrict__ conv_w,   // (64,64)
    const float* __restrict__ conv_b,   // (64,)
    const float* __restrict__ adjw,     // (N,9,9)
    float*       __restrict__ out)      // (B,N,64)
{
    __shared__ __align__(16) _Float16 ey_lds[4][ROWS * LDST];  // 4x2304 B

    const int lane = threadIdx.x & 63;
    const int wid  = threadIdx.x >> 6;
    const int quad = lane >> 4;
    const int c    = lane & 15;

    // B-fragments (held whole kernel): bfrag[s][nt][j] = W[nt*16+c][s*32+quad*8+j]
    half8 bfrag[2][4];
    #pragma unroll
    for (int s = 0; s < 2; ++s)
        #pragma unroll
        for (int nt = 0; nt < 4; ++nt) {
            const float* wp = conv_w + (nt * 16 + c) * CC + s * 32 + quad * 8;
            half8 f;
            #pragma unroll
            for (int j = 0; j < 8; ++j) f[j] = (_Float16)wp[j];
            bfrag[s][nt] = f;
        }
    const float bias = conv_b[lane];   // final output channel o == lane

    _Float16* eyw = &ey_lds[wid][0];
    const int wave_global = blockIdx.x * 4 + wid;
    const int nwaves      = gridDim.x * 4;

    for (int p = wave_global; p < BB * NN; p += nwaves) {
        // Force wave-uniform scalars so nbr/adjw loads become s_load.
        const int pu = __builtin_amdgcn_readfirstlane(p);
        const int b  = pu >> 16;
        const int n  = pu & (NN - 1);

        // Gather 9 neighbor rows (lane = f): coalesced 256B requests.
        const int* nb = nbr + ((size_t)pu) * KK;
        float xnb[KK];
        #pragma unroll
        for (int k = 0; k < KK; ++k) {
            const int idx = nb[k];                      // s_load (uniform)
            xnb[k] = x[(((size_t)b << 16) + idx) * CC + lane];
        }

        // Stage-1: 81 FMA (adjw operands in SGPRs), elu, f16, LDS write.
        const float* An = adjw + (size_t)n * (KK * KK);
        #pragma unroll
        for (int t = 0; t < KK; ++t) {
            float y = 0.0f;
            #pragma unroll
            for (int k = 0; k < KK; ++k) y = fmaf(xnb[k], An[k * KK + t], y);
            eyw[t * LDST + lane] = (_Float16)elu_f(y);  // 2 lanes/bank: free
        }
        // (rows 9..15 stale -> masked out of the max below)

        // A-frags: lane holds A[m=c][k=quad*8+j]; both 16B-aligned.
        const _Float16* ap = eyw + c * LDST + quad * 8;
        const half8 a0 = *(const half8*)(ap);        // f = quad*8 + j
        const half8 a1 = *(const half8*)(ap + 32);   // f = 32 + quad*8 + j

        floatx4 acc[4];
        #pragma unroll
        for (int nt = 0; nt < 4; ++nt) {
            acc[nt] = (floatx4){0.f, 0.f, 0.f, 0.f};
            acc[nt] = __builtin_amdgcn_mfma_f32_16x16x32_f16(a0, bfrag[0][nt], acc[nt], 0, 0, 0);
            acc[nt] = __builtin_amdgcn_mfma_f32_16x16x32_f16(a1, bfrag[1][nt], acc[nt], 0, 0, 0);
        }

        // Per-lane masked max over this lane's rows (row = quad*4+r, valid t<9):
        // quad 0/1: all 4 rows; quad 2: only r==0 (t=8); quad 3: none.
        float part[4];
        #pragma unroll
        for (int nt = 0; nt < 4; ++nt) {
            const floatx4 a = acc[nt];
            const float m01 = fmaxf(fmaxf(a[0], a[1]), fmaxf(a[2], a[3]));
            part[nt] = (quad < 2) ? m01 : ((quad == 2) ? a[0] : -INFINITY);
        }

        // Cross-quad reduce, 3 shuffles: each lane sends what its partner needs.
        // Round 1 (xor 32, q <-> q^2): end holding h0=nt(q&2), h1=nt((q&2)|1).
        const bool hiPair = (quad & 2) != 0;
        float send0 = hiPair ? part[0] : part[2];
        float send1 = hiPair ? part[1] : part[3];
        float keep0 = hiPair ? part[2] : part[0];
        float keep1 = hiPair ? part[3] : part[1];
        const float h0 = fmaxf(keep0, __shfl_xor(send0, 32, 64));
        const float h1 = fmaxf(keep1, __shfl_xor(send1, 32, 64));
        // Round 2 (xor 16, q <-> q^1): keep nt = q, send nt = q^1.
        const bool odd = (quad & 1) != 0;
        const float send2 = odd ? h0 : h1;
        const float keep2 = odd ? h1 : h0;
        const float zmax  = fmaxf(keep2, __shfl_xor(send2, 16, 64));

        float res = elu_f(zmax + bias);               // the ONE epilogue elu
        if (n == NN - 1) res = 0.0f;                  // zero_pad row, all b
        out[((size_t)pu) * CC + lane] = res;          // o == lane: coalesced
    }
}

extern "C" void kernel_launch(void* const* d_in, const int* in_sizes, int n_in,
                              void* d_out, int out_size, void* d_ws, size_t ws_size,
                              hipStream_t stream) {
    const float* x      = (const float*)d_in[0];
    // d_in[1] = t_vertex: unused by the reference
    const int*   nbr    = (const int*)d_in[2];
    const float* conv_w = (const float*)d_in[3];
    const float* conv_b = (const float*)d_in[4];
    const float* adjw   = (const float*)d_in[5];
    float*       out    = (float*)d_out;

    dim3 grid(2048), block(256);   // 8192 waves, 32 points/wave
    hipLaunchKernelGGL(paiconv_mfma, grid, block, 0, stream,
                       x, nbr, conv_w, conv_b, adjw, out);
}